// Round 8
// baseline (37.402 us; speedup 1.0000x reference)
//
#include <hip/hip_runtime.h>
#include <climits>

// B=256 rows, N=65536, half=32768.
constexpr int HALF  = 32768;
constexpr int TPB   = 256;
constexpr int CHUNK = 2048;              // elements per half-stream per block
constexpr int NCHNK = HALF / CHUNK;      // 16 chunks per row
constexpr float THRESH = 0.01f;

// ---------------- Kernel A: streaming pass ----------------
__global__ __launch_bounds__(TPB)
void main_kernel(const float* __restrict__ pred, const float* __restrict__ label,
                 float* __restrict__ part_sum, int4* __restrict__ part_idx)
{
    const int chunk = blockIdx.x, row = blockIdx.y;
    const int t = threadIdx.x, wave = t >> 6, lane = t & 63;

    const size_t rb4 = (size_t)row * (size_t)(2 * HALF / 4);
    const float4* lr4 = (const float4*)label + rb4;
    const float4* pr4 = (const float4*)pred + rb4;

    const int v0 = chunk * (CHUNK / 4) + t;          // coalesced: lane l -> float4 l
    const int v1 = v0 + TPB;
    const int H4 = HALF / 4;

    float4 a0 = lr4[v0],      a1 = lr4[v1];
    float4 b0 = lr4[v0 + H4], b1 = lr4[v1 + H4];
    float4 p0 = pr4[v0],      p1 = pr4[v1];
    float4 q0 = pr4[v0 + H4], q1 = pr4[v1 + H4];

    float sum = 0.f;
    int minr = INT_MAX, maxr = -1, mini = INT_MAX, maxi = -1;

#define STEP(ax, bx, px, qx, idx)                                 \
    {                                                             \
        float dr = (px) - (ax), di = (qx) - (bx);                 \
        float lint = (ax) * (ax) + (bx) * (bx);                   \
        float pint = (px) * (px) + (qx) * (qx);                   \
        float dd = pint - lint;                                   \
        sum += dr * dr + di * di + 50.f * dd * dd;                \
        if (fabsf(ax) > THRESH) {                                 \
            minr = min(minr, (idx)); maxr = max(maxr, (idx));     \
        }                                                         \
        if (fabsf(bx) > THRESH) {                                 \
            mini = min(mini, (idx)); maxi = max(maxi, (idx));     \
        }                                                         \
    }
    {
        const int base = v0 * 4;
        STEP(a0.x, b0.x, p0.x, q0.x, base + 0)
        STEP(a0.y, b0.y, p0.y, q0.y, base + 1)
        STEP(a0.z, b0.z, p0.z, q0.z, base + 2)
        STEP(a0.w, b0.w, p0.w, q0.w, base + 3)
    }
    {
        const int base = v1 * 4;
        STEP(a1.x, b1.x, p1.x, q1.x, base + 0)
        STEP(a1.y, b1.y, p1.y, q1.y, base + 1)
        STEP(a1.z, b1.z, p1.z, q1.z, base + 2)
        STEP(a1.w, b1.w, p1.w, q1.w, base + 3)
    }
#undef STEP

    #pragma unroll
    for (int off = 32; off > 0; off >>= 1) {
        sum += __shfl_down(sum, off);
        minr = min(minr, __shfl_down(minr, off));
        maxr = max(maxr, __shfl_down(maxr, off));
        mini = min(mini, __shfl_down(mini, off));
        maxi = max(maxi, __shfl_down(maxi, off));
    }

    __shared__ float s_sum[4];
    __shared__ int   s_idx[4][4];
    if (lane == 0) {
        s_sum[wave] = sum;
        s_idx[wave][0] = minr; s_idx[wave][1] = maxr;
        s_idx[wave][2] = mini; s_idx[wave][3] = maxi;
    }
    __syncthreads();
    if (t == 0) {
        float S = 0.f; int mr = INT_MAX, Mr = -1, mi = INT_MAX, Mi = -1;
        #pragma unroll
        for (int w = 0; w < 4; ++w) {
            S += s_sum[w];
            mr = min(mr, s_idx[w][0]); Mr = max(Mr, s_idx[w][1]);
            mi = min(mi, s_idx[w][2]); Mi = max(Mi, s_idx[w][3]);
        }
        const int slot = row * NCHNK + chunk;        // [row][chunk]
        part_sum[slot] = S;
        part_idx[slot] = make_int4(mr, Mr, mi, Mi);
    }
}

// ---------------- Kernel B: per-row edges + last-block final reduce ----------------
__global__ __launch_bounds__(TPB)
void tail_kernel(const float* __restrict__ pred, const float* __restrict__ label,
                 const float* __restrict__ part_sum, const int4* __restrict__ part_idx,
                 float* __restrict__ row_tot, unsigned* __restrict__ counter,
                 float* __restrict__ out, int rows)
{
    const int row = blockIdx.x;
    const int t = threadIdx.x, wave = t >> 6, lane = t & 63;

    float base = 0.f;
    int fr = INT_MAX, lastr = -1, fi = INT_MAX, lasti = -1;
    #pragma unroll
    for (int s = 0; s < NCHNK; ++s) {
        base += part_sum[row * NCHNK + s];
        int4 v = part_idx[row * NCHNK + s];
        fr = min(fr, v.x); lastr = max(lastr, v.y);
        fi = min(fi, v.z); lasti = max(lasti, v.w);
    }
    if (lastr < 0) { fr = 0; lastr = HALF - 1; }
    if (lasti < 0) { fi = 0; lasti = HALF - 1; }

    const float* Lr = label + (size_t)row * (2 * HALF);
    const float* Li = Lr + HALF;
    const float* Pr = pred + (size_t)row * (2 * HALF);
    const float* Pi = Pr + HALF;

    // extra +1*d^2 outside [first,last] (typically ~0-2 elements per edge)
    float ex = 0.f;
    for (int i = t; i < fr; i += TPB)               { float d = Pr[i] - Lr[i]; ex += d * d; }
    for (int i = lastr + 1 + t; i < HALF; i += TPB) { float d = Pr[i] - Lr[i]; ex += d * d; }
    for (int i = t; i < fi; i += TPB)               { float d = Pi[i] - Li[i]; ex += d * d; }
    for (int i = lasti + 1 + t; i < HALF; i += TPB) { float d = Pi[i] - Li[i]; ex += d * d; }

    #pragma unroll
    for (int off = 32; off > 0; off >>= 1) ex += __shfl_down(ex, off);
    __shared__ float s_ex[4];
    if (lane == 0) s_ex[wave] = ex;
    __syncthreads();

    __shared__ bool s_last;
    if (t == 0) {
        float rv = base + s_ex[0] + s_ex[1] + s_ex[2] + s_ex[3];
        // device-scope atomic write (coherent across XCDs), then fence, then count
        atomicExch(&row_tot[row], rv);
        __threadfence();
        unsigned old = atomicAdd(counter, 1u);
        s_last = (old == (unsigned)(gridDim.x - 1));
    }
    __syncthreads();

    if (s_last) {
        // last block: all other blocks' atomicExch happened-before their
        // counter bump -> device-coherent atomic reads see final values.
        float v = 0.f;
        if (t < rows) v = atomicAdd(&row_tot[t], 0.0f);   // atomic read (returns old)
        #pragma unroll
        for (int off = 32; off > 0; off >>= 1) v += __shfl_down(v, off);
        __shared__ float sf[4];
        if (lane == 0) sf[wave] = v;
        __syncthreads();
        if (t == 0)
            out[0] = (sf[0] + sf[1] + sf[2] + sf[3]) * (1.0f / ((float)HALF * (float)rows));
    }
}

extern "C" void kernel_launch(void* const* d_in, const int* in_sizes, int n_in,
                              void* d_out, int out_size, void* d_ws, size_t ws_size,
                              hipStream_t stream) {
    const float* pred  = (const float*)d_in[0];
    const float* label = (const float*)d_in[1];
    float* out = (float*)d_out;

    const int rows = in_sizes[0] / (2 * HALF);   // 256
    const int nslots = rows * NCHNK;             // 4096

    float*    part_sum = (float*)d_ws;                               // 16 KB
    int4*     part_idx = (int4*)((char*)d_ws + nslots * 4);          // 64 KB (16B-aligned)
    float*    row_tot  = (float*)((char*)d_ws + nslots * 4 + nslots * 16);
    unsigned* counter  = (unsigned*)((char*)d_ws + nslots * 4 + nslots * 16 + rows * 4);

    hipMemsetAsync(counter, 0, sizeof(unsigned), stream);   // graph-capturable

    dim3 gridA(NCHNK, rows);
    main_kernel<<<gridA, TPB, 0, stream>>>(pred, label, part_sum, part_idx);
    tail_kernel<<<rows, TPB, 0, stream>>>(pred, label, part_sum, part_idx,
                                          row_tot, counter, out, rows);
}

// Round 9
// 31.938 us; speedup vs baseline: 1.1711x; 1.1711x over previous
//
#include <hip/hip_runtime.h>
#include <climits>

// B=256 rows, N=65536, half=32768.
constexpr int HALF  = 32768;
constexpr int TPB   = 256;
constexpr int CHUNK = 2048;              // elements per half-stream per block
constexpr int NCHNK = HALF / CHUNK;      // 16 chunks per row
constexpr float THRESH = 0.01f;

// Per-(row,chunk) ordered-monoid leaf, computed fully in-block:
//   per stream: (sum d^2, sum-before-first-significant, sum-after-last-significant, has)
//   invariant: has==0 -> pre==post==sum
// plus sum of (dint)^2. Tail folds 16 leaves per row in chunk order.

__global__ __launch_bounds__(TPB)
void main_kernel(const float* __restrict__ pred, const float* __restrict__ label,
                 float4* __restrict__ slots, int rows)
{
    const int chunk = blockIdx.x, row = blockIdx.y;
    const int t = threadIdx.x, wave = t >> 6, lane = t & 63;

    const size_t rb4 = (size_t)row * (size_t)(2 * HALF / 4);
    const float4* lr4 = (const float4*)label + rb4;
    const float4* pr4 = (const float4*)pred + rb4;

    const int v0 = chunk * (CHUNK / 4) + t;          // coalesced: lane l -> float4 l
    const int v1 = v0 + TPB;
    const int H4 = HALF / 4;

    float4 a0 = lr4[v0],      a1 = lr4[v1];
    float4 b0 = lr4[v0 + H4], b1 = lr4[v1 + H4];
    float4 p0 = pr4[v0],      p1 = pr4[v1];
    float4 q0 = pr4[v0 + H4], q1 = pr4[v1 + H4];

    // ---- phase 1: squared diffs (held in regs), sums, chunk-local min/max idx ----
    float cr[8], ci[8];
    float sum_r = 0.f, sum_i = 0.f, sum_dd = 0.f;
    int minr = INT_MAX, maxr = -1, mini = INT_MAX, maxi = -1;

    // chunk-local element indices: group0 -> t*4+e, group1 -> 1024 + t*4+e
#define STEP(k, ax, bx, px, qx, li)                               \
    {                                                             \
        float dr = (px) - (ax), di = (qx) - (bx);                 \
        cr[k] = dr * dr; ci[k] = di * di;                         \
        float lint = (ax) * (ax) + (bx) * (bx);                   \
        float pint = (px) * (px) + (qx) * (qx);                   \
        float dd = pint - lint;                                   \
        sum_dd += dd * dd;                                        \
        sum_r += cr[k]; sum_i += ci[k];                           \
        if (fabsf(ax) > THRESH) {                                 \
            minr = min(minr, (li)); maxr = max(maxr, (li));       \
        }                                                         \
        if (fabsf(bx) > THRESH) {                                 \
            mini = min(mini, (li)); maxi = max(maxi, (li));       \
        }                                                         \
    }
    {
        const int l0 = t * 4;
        STEP(0, a0.x, b0.x, p0.x, q0.x, l0 + 0)
        STEP(1, a0.y, b0.y, p0.y, q0.y, l0 + 1)
        STEP(2, a0.z, b0.z, p0.z, q0.z, l0 + 2)
        STEP(3, a0.w, b0.w, p0.w, q0.w, l0 + 3)
        const int l1 = 1024 + t * 4;                 // CHUNK/2 = 1024
        STEP(4, a1.x, b1.x, p1.x, q1.x, l1 + 0)
        STEP(5, a1.y, b1.y, p1.y, q1.y, l1 + 1)
        STEP(6, a1.z, b1.z, p1.z, q1.z, l1 + 2)
        STEP(7, a1.w, b1.w, p1.w, q1.w, l1 + 3)
    }
#undef STEP

    // block min/max reduce of 4 indices
    #pragma unroll
    for (int off = 32; off > 0; off >>= 1) {
        minr = min(minr, __shfl_down(minr, off));
        maxr = max(maxr, __shfl_down(maxr, off));
        mini = min(mini, __shfl_down(mini, off));
        maxi = max(maxi, __shfl_down(maxi, off));
    }
    __shared__ int s_idx[4][4];
    __shared__ int s_bcast[4];           // FR, LR, FI, LI (chunk-local)
    if (lane == 0) {
        s_idx[wave][0] = minr; s_idx[wave][1] = maxr;
        s_idx[wave][2] = mini; s_idx[wave][3] = maxi;
    }
    __syncthreads();
    if (t == 0) {
        int mr = INT_MAX, Mr = -1, mi = INT_MAX, Mi = -1;
        #pragma unroll
        for (int w = 0; w < 4; ++w) {
            mr = min(mr, s_idx[w][0]); Mr = max(Mr, s_idx[w][1]);
            mi = min(mi, s_idx[w][2]); Mi = max(Mi, s_idx[w][3]);
        }
        s_bcast[0] = mr; s_bcast[1] = Mr; s_bcast[2] = mi; s_bcast[3] = Mi;
    }
    __syncthreads();
    const int FR = s_bcast[0], LR = s_bcast[1], FI = s_bcast[2], LI = s_bcast[3];

    // ---- phase 2: masked pre/post sums (leaf monoid values) ----
    // FR==INT_MAX (no sig): all idx < FR -> pre = sum. LR==-1: all > LR -> post = sum.
    float pre_r = 0.f, post_r = 0.f, pre_i = 0.f, post_i = 0.f;
    #pragma unroll
    for (int k = 0; k < 8; ++k) {
        const int li = (k < 4) ? (t * 4 + k) : (1024 + t * 4 + (k - 4));
        pre_r  += (li < FR) ? cr[k] : 0.f;
        post_r += (li > LR) ? cr[k] : 0.f;
        pre_i  += (li < FI) ? ci[k] : 0.f;
        post_i += (li > LI) ? ci[k] : 0.f;
    }

    // reduce 7 sums
    #pragma unroll
    for (int off = 32; off > 0; off >>= 1) {
        sum_r  += __shfl_down(sum_r,  off);
        sum_i  += __shfl_down(sum_i,  off);
        sum_dd += __shfl_down(sum_dd, off);
        pre_r  += __shfl_down(pre_r,  off);
        post_r += __shfl_down(post_r, off);
        pre_i  += __shfl_down(pre_i,  off);
        post_i += __shfl_down(post_i, off);
    }
    __shared__ float s_red[4][7];
    if (lane == 0) {
        float* d = s_red[wave];
        d[0] = sum_r; d[1] = pre_r; d[2] = post_r;
        d[3] = sum_i; d[4] = pre_i; d[5] = post_i;
        d[6] = sum_dd;
    }
    __syncthreads();
    if (t == 0) {
        float v[7] = {0, 0, 0, 0, 0, 0, 0};
        #pragma unroll
        for (int w = 0; w < 4; ++w)
            #pragma unroll
            for (int k = 0; k < 7; ++k) v[k] += s_red[w][k];
        const float has_r = (LR >= 0) ? 1.f : 0.f;
        const float has_i = (LI >= 0) ? 1.f : 0.f;
        float4* s = &slots[((size_t)chunk * rows + row) * 3];   // [chunk][row]
        s[0] = make_float4(v[0], v[1], v[2], has_r);
        s[1] = make_float4(v[3], v[4], v[5], has_i);
        s[2] = make_float4(v[6], 0.f, 0.f, 0.f);
    }
}

// ---------------- Tail: one block; thread r folds row r's 16 leaves ----------------
__global__ __launch_bounds__(TPB)
void tail_kernel(const float4* __restrict__ slots, float* __restrict__ out, int rows)
{
    const int t = threadIdx.x, wave = t >> 6, lane = t & 63;

    float total = 0.f;
    if (t < rows) {
        float rs = 0.f, rp = 0.f, rq = 0.f; int rh = 0;
        float is_ = 0.f, ip = 0.f, iq = 0.f; int ih = 0;
        float ds = 0.f;
        #pragma unroll
        for (int c = 0; c < NCHNK; ++c) {
            const float4* s = &slots[((size_t)c * rows + t) * 3];
            float4 A = s[0], B = s[1], C = s[2];
            rp = rh ? rp : (rs + A.y);
            rq = (A.w != 0.f) ? A.z : (rq + A.x);
            rs += A.x; rh |= (A.w != 0.f);
            ip = ih ? ip : (is_ + B.y);
            iq = (B.w != 0.f) ? B.z : (iq + B.x);
            is_ += B.x; ih |= (B.w != 0.f);
            ds += C.x;
        }
        total = rs + is_ + 50.f * ds
              + (rh ? (rp + rq) : 0.f) + (ih ? (ip + iq) : 0.f);
    }

    #pragma unroll
    for (int off = 32; off > 0; off >>= 1) total += __shfl_down(total, off);
    __shared__ float sf[4];
    if (lane == 0) sf[wave] = total;
    __syncthreads();
    if (t == 0)
        out[0] = (sf[0] + sf[1] + sf[2] + sf[3]) * (1.0f / ((float)HALF * (float)rows));
}

extern "C" void kernel_launch(void* const* d_in, const int* in_sizes, int n_in,
                              void* d_out, int out_size, void* d_ws, size_t ws_size,
                              hipStream_t stream) {
    const float* pred  = (const float*)d_in[0];
    const float* label = (const float*)d_in[1];
    float* out = (float*)d_out;

    const int rows = in_sizes[0] / (2 * HALF);   // 256
    float4* slots = (float4*)d_ws;               // NCHNK*rows*3 float4 = 192 KB

    dim3 gridA(NCHNK, rows);
    main_kernel<<<gridA, TPB, 0, stream>>>(pred, label, slots, rows);
    tail_kernel<<<1, TPB, 0, stream>>>(slots, out, rows);
}

// Round 10
// 29.645 us; speedup vs baseline: 1.2616x; 1.0773x over previous
//
#include <hip/hip_runtime.h>
#include <hip/hip_cooperative_groups.h>
#include <climits>

namespace cg = cooperative_groups;

// B=256 rows, N=65536, half=32768.
constexpr int HALF  = 32768;
constexpr int TPB   = 256;
constexpr int CHUNK = 2048;              // elements per half-stream per block
constexpr int NCHNK = HALF / CHUNK;      // 16 chunks per row
constexpr int ROWS  = 256;
constexpr int NBLK  = NCHNK * ROWS;      // 2048 blocks (8 per CU at 256 thr)
constexpr float THRESH = 0.01f;

// Agent-scope (device-coherent) accessors — required because per-XCD L2s are
// not coherent and block->XCD mapping varies between graph replays.
__device__ __forceinline__ void st_ag(float* p, float v) {
    __hip_atomic_store(p, v, __ATOMIC_RELAXED, __HIP_MEMORY_SCOPE_AGENT);
}
__device__ __forceinline__ float ld_ag(const float* p) {
    return __hip_atomic_load(p, __ATOMIC_RELAXED, __HIP_MEMORY_SCOPE_AGENT);
}
__device__ __forceinline__ void st_ag_i(int* p, int v) {
    __hip_atomic_store(p, v, __ATOMIC_RELAXED, __HIP_MEMORY_SCOPE_AGENT);
}
__device__ __forceinline__ int ld_ag_i(const int* p) {
    return __hip_atomic_load(p, __ATOMIC_RELAXED, __HIP_MEMORY_SCOPE_AGENT);
}

// Shared phase-1 math (identical to the proven R6 main kernel).
template <typename SUMF, typename IDXF>
__device__ __forceinline__ void phase1_body(const float* __restrict__ pred,
                                            const float* __restrict__ label,
                                            int chunk, int row, int t, int wave, int lane,
                                            SUMF&& emit_sum, IDXF&& emit_idx)
{
    const size_t rb4 = (size_t)row * (size_t)(2 * HALF / 4);
    const float4* lr4 = (const float4*)label + rb4;
    const float4* pr4 = (const float4*)pred + rb4;

    const int v0 = chunk * (CHUNK / 4) + t;
    const int v1 = v0 + TPB;
    const int H4 = HALF / 4;

    float4 a0 = lr4[v0],      a1 = lr4[v1];
    float4 b0 = lr4[v0 + H4], b1 = lr4[v1 + H4];
    float4 p0 = pr4[v0],      p1 = pr4[v1];
    float4 q0 = pr4[v0 + H4], q1 = pr4[v1 + H4];

    float sum = 0.f;
    int minr = INT_MAX, maxr = -1, mini = INT_MAX, maxi = -1;

#define STEP(ax, bx, px, qx, idx)                                 \
    {                                                             \
        float dr = (px) - (ax), di = (qx) - (bx);                 \
        float lint = (ax) * (ax) + (bx) * (bx);                   \
        float pint = (px) * (px) + (qx) * (qx);                   \
        float dd = pint - lint;                                   \
        sum += dr * dr + di * di + 50.f * dd * dd;                \
        if (fabsf(ax) > THRESH) {                                 \
            minr = min(minr, (idx)); maxr = max(maxr, (idx));     \
        }                                                         \
        if (fabsf(bx) > THRESH) {                                 \
            mini = min(mini, (idx)); maxi = max(maxi, (idx));     \
        }                                                         \
    }
    {
        const int base = v0 * 4;
        STEP(a0.x, b0.x, p0.x, q0.x, base + 0)
        STEP(a0.y, b0.y, p0.y, q0.y, base + 1)
        STEP(a0.z, b0.z, p0.z, q0.z, base + 2)
        STEP(a0.w, b0.w, p0.w, q0.w, base + 3)
    }
    {
        const int base = v1 * 4;
        STEP(a1.x, b1.x, p1.x, q1.x, base + 0)
        STEP(a1.y, b1.y, p1.y, q1.y, base + 1)
        STEP(a1.z, b1.z, p1.z, q1.z, base + 2)
        STEP(a1.w, b1.w, p1.w, q1.w, base + 3)
    }
#undef STEP

    #pragma unroll
    for (int off = 32; off > 0; off >>= 1) {
        sum += __shfl_down(sum, off);
        minr = min(minr, __shfl_down(minr, off));
        maxr = max(maxr, __shfl_down(maxr, off));
        mini = min(mini, __shfl_down(mini, off));
        maxi = max(maxi, __shfl_down(maxi, off));
    }

    __shared__ float s_sum[4];
    __shared__ int   s_idx[4][4];
    if (lane == 0) {
        s_sum[wave] = sum;
        s_idx[wave][0] = minr; s_idx[wave][1] = maxr;
        s_idx[wave][2] = mini; s_idx[wave][3] = maxi;
    }
    __syncthreads();
    if (t == 0) {
        float S = 0.f; int mr = INT_MAX, Mr = -1, mi = INT_MAX, Mi = -1;
        #pragma unroll
        for (int w = 0; w < 4; ++w) {
            S += s_sum[w];
            mr = min(mr, s_idx[w][0]); Mr = max(Mr, s_idx[w][1]);
            mi = min(mi, s_idx[w][2]); Mi = max(Mi, s_idx[w][3]);
        }
        emit_sum(S);
        emit_idx(mr, Mr, mi, Mi);
    }
}

// ---------------- Fused cooperative kernel ----------------
__global__ __launch_bounds__(TPB, 8)
void fused_kernel(const float* __restrict__ pred, const float* __restrict__ label,
                  float* __restrict__ part_sum, int* __restrict__ part_idx,
                  float* __restrict__ row_tot, float* __restrict__ out)
{
    cg::grid_group grid = cg::this_grid();
    const int bid = blockIdx.x;
    const int chunk = bid & (NCHNK - 1);
    const int row = bid >> 4;
    const int t = threadIdx.x, wave = t >> 6, lane = t & 63;

    // ---- phase 1: streaming pass ----
    {
        const int slot = row * NCHNK + chunk;
        phase1_body(pred, label, chunk, row, t, wave, lane,
            [&](float S) { st_ag(&part_sum[slot], S); },
            [&](int mr, int Mr, int mi, int Mi) {
                st_ag_i(&part_idx[slot * 4 + 0], mr);
                st_ag_i(&part_idx[slot * 4 + 1], Mr);
                st_ag_i(&part_idx[slot * 4 + 2], mi);
                st_ag_i(&part_idx[slot * 4 + 3], Mi);
            });
    }

    grid.sync();

    // ---- phase 2: blocks 0..ROWS-1 fold their row + edge sums ----
    if (bid < ROWS) {
        const int r = bid;
        __shared__ float sh_sum[NCHNK];
        __shared__ int   sh_i[NCHNK][4];
        if (t < NCHNK) {
            const int slot = r * NCHNK + t;
            sh_sum[t]  = ld_ag(&part_sum[slot]);
            sh_i[t][0] = ld_ag_i(&part_idx[slot * 4 + 0]);
            sh_i[t][1] = ld_ag_i(&part_idx[slot * 4 + 1]);
            sh_i[t][2] = ld_ag_i(&part_idx[slot * 4 + 2]);
            sh_i[t][3] = ld_ag_i(&part_idx[slot * 4 + 3]);
        }
        __syncthreads();

        __shared__ float sh_base;
        __shared__ int   sh_b[4];
        if (t == 0) {
            float S = 0.f; int fr = INT_MAX, lr = -1, fi = INT_MAX, li = -1;
            #pragma unroll
            for (int c = 0; c < NCHNK; ++c) {
                S += sh_sum[c];
                fr = min(fr, sh_i[c][0]); lr = max(lr, sh_i[c][1]);
                fi = min(fi, sh_i[c][2]); li = max(li, sh_i[c][3]);
            }
            if (lr < 0) { fr = 0; lr = HALF - 1; }
            if (li < 0) { fi = 0; li = HALF - 1; }
            sh_base = S;
            sh_b[0] = fr; sh_b[1] = lr; sh_b[2] = fi; sh_b[3] = li;
        }
        __syncthreads();
        const int fr = sh_b[0], lr = sh_b[1], fi = sh_b[2], li = sh_b[3];

        const float* Lr = label + (size_t)r * (2 * HALF);
        const float* Li = Lr + HALF;
        const float* Pr = pred + (size_t)r * (2 * HALF);
        const float* Pi = Pr + HALF;

        float ex = 0.f;   // extra +1*d^2 outside [first,last]
        for (int i = t; i < fr; i += TPB)            { float d = Pr[i] - Lr[i]; ex += d * d; }
        for (int i = lr + 1 + t; i < HALF; i += TPB) { float d = Pr[i] - Lr[i]; ex += d * d; }
        for (int i = t; i < fi; i += TPB)            { float d = Pi[i] - Li[i]; ex += d * d; }
        for (int i = li + 1 + t; i < HALF; i += TPB) { float d = Pi[i] - Li[i]; ex += d * d; }

        #pragma unroll
        for (int off = 32; off > 0; off >>= 1) ex += __shfl_down(ex, off);
        __shared__ float s_ex[4];
        if (lane == 0) s_ex[wave] = ex;
        __syncthreads();
        if (t == 0)
            st_ag(&row_tot[r], sh_base + s_ex[0] + s_ex[1] + s_ex[2] + s_ex[3]);
    }

    grid.sync();

    // ---- phase 3: block 0 final reduce ----
    if (bid == 0) {
        float v = (t < ROWS) ? ld_ag(&row_tot[t]) : 0.f;
        #pragma unroll
        for (int off = 32; off > 0; off >>= 1) v += __shfl_down(v, off);
        __shared__ float sf[4];
        if (lane == 0) sf[wave] = v;
        __syncthreads();
        if (t == 0)
            out[0] = (sf[0] + sf[1] + sf[2] + sf[3]) * (1.0f / ((float)HALF * (float)ROWS));
    }
}

// ---------------- Fallback: proven 3-dispatch path (R6) ----------------
__global__ __launch_bounds__(TPB)
void main_kernel(const float* __restrict__ pred, const float* __restrict__ label,
                 float* __restrict__ part_sum, int* __restrict__ part_idx)
{
    const int chunk = blockIdx.x, row = blockIdx.y;
    const int t = threadIdx.x, wave = t >> 6, lane = t & 63;
    const int slot = row * NCHNK + chunk;
    phase1_body(pred, label, chunk, row, t, wave, lane,
        [&](float S) { part_sum[slot] = S; },
        [&](int mr, int Mr, int mi, int Mi) {
            part_idx[slot * 4 + 0] = mr; part_idx[slot * 4 + 1] = Mr;
            part_idx[slot * 4 + 2] = mi; part_idx[slot * 4 + 3] = Mi;
        });
}

__global__ __launch_bounds__(TPB)
void edge_kernel(const float* __restrict__ pred, const float* __restrict__ label,
                 const float* __restrict__ part_sum, const int* __restrict__ part_idx,
                 float* __restrict__ row_tot)
{
    const int row = blockIdx.x;
    const int t = threadIdx.x, wave = t >> 6, lane = t & 63;

    float base = 0.f;
    int fr = INT_MAX, lr = -1, fi = INT_MAX, li = -1;
    #pragma unroll
    for (int s = 0; s < NCHNK; ++s) {
        const int slot = row * NCHNK + s;
        base += part_sum[slot];
        fr = min(fr, part_idx[slot * 4 + 0]); lr = max(lr, part_idx[slot * 4 + 1]);
        fi = min(fi, part_idx[slot * 4 + 2]); li = max(li, part_idx[slot * 4 + 3]);
    }
    if (lr < 0) { fr = 0; lr = HALF - 1; }
    if (li < 0) { fi = 0; li = HALF - 1; }

    const float* Lr = label + (size_t)row * (2 * HALF);
    const float* Li = Lr + HALF;
    const float* Pr = pred + (size_t)row * (2 * HALF);
    const float* Pi = Pr + HALF;

    float ex = 0.f;
    for (int i = t; i < fr; i += TPB)            { float d = Pr[i] - Lr[i]; ex += d * d; }
    for (int i = lr + 1 + t; i < HALF; i += TPB) { float d = Pr[i] - Lr[i]; ex += d * d; }
    for (int i = t; i < fi; i += TPB)            { float d = Pi[i] - Li[i]; ex += d * d; }
    for (int i = li + 1 + t; i < HALF; i += TPB) { float d = Pi[i] - Li[i]; ex += d * d; }

    #pragma unroll
    for (int off = 32; off > 0; off >>= 1) ex += __shfl_down(ex, off);
    __shared__ float s_ex[4];
    if (lane == 0) s_ex[wave] = ex;
    __syncthreads();
    if (t == 0)
        row_tot[row] = base + s_ex[0] + s_ex[1] + s_ex[2] + s_ex[3];
}

__global__ void finalize_kernel(const float* __restrict__ row_tot,
                                float* __restrict__ out, int rows)
{
    const int t = threadIdx.x;
    float v = 0.f;
    for (int i = t; i < rows; i += 256) v += row_tot[i];
    #pragma unroll
    for (int off = 32; off > 0; off >>= 1) v += __shfl_down(v, off);
    __shared__ float s[4];
    if ((t & 63) == 0) s[t >> 6] = v;
    __syncthreads();
    if (t == 0)
        out[0] = (s[0] + s[1] + s[2] + s[3]) * (1.0f / ((float)HALF * (float)rows));
}

extern "C" void kernel_launch(void* const* d_in, const int* in_sizes, int n_in,
                              void* d_out, int out_size, void* d_ws, size_t ws_size,
                              hipStream_t stream) {
    const float* pred  = (const float*)d_in[0];
    const float* label = (const float*)d_in[1];
    float* out = (float*)d_out;

    const int nslots = ROWS * NCHNK;                                 // 4096
    float* part_sum = (float*)d_ws;                                  // 16 KB
    int*   part_idx = (int*)((char*)d_ws + nslots * 4);              // 64 KB
    float* row_tot  = (float*)((char*)d_ws + nslots * 4 + nslots * 16);

    // Capture-safe host queries: can the cooperative grid be co-resident?
    int dev = 0; hipGetDevice(&dev);
    int num_cu = 0;
    hipDeviceGetAttribute(&num_cu, hipDeviceAttributeMultiprocessorCount, dev);
    int max_blk_per_cu = 0;
    hipError_t occ_err = hipOccupancyMaxActiveBlocksPerMultiprocessor(
        &max_blk_per_cu, fused_kernel, TPB, 0);

    bool coop_ok = (occ_err == hipSuccess) && (max_blk_per_cu * num_cu >= NBLK);

    if (coop_ok) {
        void* args[] = { (void*)&pred, (void*)&label, (void*)&part_sum,
                         (void*)&part_idx, (void*)&row_tot, (void*)&out };
        hipError_t err = hipLaunchCooperativeKernel(
            (const void*)fused_kernel, dim3(NBLK), dim3(TPB), args, 0, stream);
        if (err == hipSuccess) return;
        // fall through to the 3-dispatch path on any launch failure
    }

    dim3 gridA(NCHNK, ROWS);
    main_kernel<<<gridA, TPB, 0, stream>>>(pred, label, part_sum, part_idx);
    edge_kernel<<<ROWS, TPB, 0, stream>>>(pred, label, part_sum, part_idx, row_tot);
    finalize_kernel<<<1, TPB, 0, stream>>>(row_tot, out, ROWS);
}